// Round 3
// baseline (12093.912 us; speedup 1.0000x reference)
//
#include <hip/hip_runtime.h>
#include <hip/hip_bf16.h>

#define B_   64
#define T_   512
#define DIN_ 256
#define H_   512

typedef __attribute__((ext_vector_type(2))) _Float16 h16x2;
typedef __attribute__((ext_vector_type(8))) _Float16 h16x8;
typedef __attribute__((ext_vector_type(2))) __fp16  fp16x2r;  // cvt_pkrtz return type
typedef __attribute__((ext_vector_type(4))) float f32x4;
typedef unsigned short u16;

__device__ __forceinline__ float sigmf(float xv) {
  return 1.0f / (1.0f + __expf(-xv));
}

__device__ __forceinline__ void spinwait(unsigned* p, unsigned target) {
  int guard = 0;
  while (__hip_atomic_load(p, __ATOMIC_RELAXED, __HIP_MEMORY_SCOPE_AGENT) < target) {
    __builtin_amdgcn_s_sleep(2);
    if (++guard > (1 << 20)) break;   // safety valve: never hang the harness
  }
}

__device__ __forceinline__ h16x8 pk8(f32x4 a, f32x4 b) {
  union { h16x8 h; fp16x2r p[4]; } u;   // __fp16 member matches cvt_pkrtz return
  u.p[0] = __builtin_amdgcn_cvt_pkrtz(a.x, a.y);
  u.p[1] = __builtin_amdgcn_cvt_pkrtz(a.z, a.w);
  u.p[2] = __builtin_amdgcn_cvt_pkrtz(b.x, b.y);
  u.p[3] = __builtin_amdgcn_cvt_pkrtz(b.z, b.w);
  return u.h;
}

// Persistent per-WG LSTM slice. Data is FP32 in global memory (proven by the
// round-1 NaN: only fp32-as-bf16 reinterpretation can synthesize NaN bits).
// Compute: W staged once f32->fp16 in LDS; MFMA 16x16x32 f16 with fp32 accum;
// c/biases/hn/cn in fp32; h exchanged through fp16 rings in ws.
// WG owns 16 hidden units (64 gate-rows, gate-interleaved rho: gate=rho&3,
// j_in_4=(rho>>2)&3, tile=rho>>4) for one batch group of 32. Gates i,f,g,o of
// a unit land in 4 adjacent lanes of the MFMA D tile -> quad __shfl update.
template <int LAYER>
__device__ __forceinline__ void lstm_body(
    const float* __restrict__ xin,
    const float* __restrict__ Wih, const float* __restrict__ Whh,
    const float* __restrict__ bih, const float* __restrict__ bhh,
    float* __restrict__ out,
    unsigned* __restrict__ done0, unsigned* __restrict__ done1,
    u16* __restrict__ h0ring, u16* __restrict__ h1ring,
    _Float16* wlds, int g, int j0)
{
  constexpr int K    = LAYER ? 1024 : 768;   // Kih + 512 (recurrent)
  constexpr int KP   = K + 8;                // pad keeps rows 16B-aligned, breaks bank stride
  constexpr int KIH  = LAYER ? 512 : 256;
  constexpr int NKB1 = KIH / 32;
  const int tid = threadIdx.x;

  // ---- one-time: stage W slice (64 rows x K) f32 -> fp16 LDS ----
  {
    const int c = tid;                       // float4 chunk within a row
    if (c < (K >> 2)) {
      for (int rho = 0; rho < 64; ++rho) {
        const int gI = rho & 3, jI = (rho >> 2) & 3, nt = rho >> 4;
        const int gr = gI * H_ + j0 + nt * 4 + jI;   // global gate-row
        f32x4 v;
        if (c < (KIH >> 2))
          v = *(const f32x4*)(Wih + (size_t)gr * KIH + (size_t)c * 4);
        else
          v = *(const f32x4*)(Whh + (size_t)gr * H_ + (size_t)(c - (KIH >> 2)) * 4);
        h16x2 q0, q1;                        // scalar casts: RTN rounding for weights
        q0[0] = (_Float16)v.x; q0[1] = (_Float16)v.y;
        q1[0] = (_Float16)v.z; q1[1] = (_Float16)v.w;
        *(h16x2*)(wlds + rho * KP + c * 4)     = q0;
        *(h16x2*)(wlds + rho * KP + c * 4 + 2) = q1;
      }
    }
  }

  const int lane = tid & 63;
  const int w    = tid >> 6;        // wave id == N-tile id
  const int n    = lane & 15;       // output col within 16-wide tile
  const int quad = lane >> 4;
  const int gI   = n & 3;           // gate of this lane's column
  const int jI   = n >> 2;
  const int jglob = j0 + w * 4 + jI;
  const float bias = bih[gI * H_ + jglob] + bhh[gI * H_ + jglob];

  const int mRow0 = g * 32 + n;          // A-operand rows (m = lane&15)
  const int mRow1 = g * 32 + 16 + n;
  const int koffA = quad * 8;            // k offset within 32-wide k-block
  const _Float16* bbase = wlds + (w * 16 + n) * KP + koffA;

  __syncthreads();

  f32x4 cstate[2] = {{0.f,0.f,0.f,0.f},{0.f,0.f,0.f,0.f}};
  unsigned* myDone = LAYER ? done1 : done0;

  for (int t = 0; t < T_; ++t) {
    if (tid == 0) {
      if (LAYER == 0) {
        if (t > 0) spinwait(&done0[g * T_ + t - 1], 32);   // peers' h0[t-1]
        if (t >= 8) spinwait(&done1[g * T_ + t - 8], 32);  // ring backpressure
      } else {
        spinwait(&done0[g * T_ + t], 32);                  // h0[t] ready
        if (t > 0) spinwait(&done1[g * T_ + t - 1], 32);   // peers' h1[t-1]
      }
    }
    __syncthreads();
    __threadfence();   // acquire: peers' h stores (possibly other XCD)

    f32x4 acc0 = {0.f,0.f,0.f,0.f}, acc1 = {0.f,0.f,0.f,0.f};

    // part 1: W_ih * input_t   (L0: x_t fp32->fp16 pack ; L1: h0[t] fp16 ring)
    if (LAYER == 0) {
      const float* a0 = xin + (size_t)mRow0 * (T_ * DIN_) + (size_t)t * DIN_ + koffA;
      const float* a1 = xin + (size_t)mRow1 * (T_ * DIN_) + (size_t)t * DIN_ + koffA;
#pragma unroll
      for (int kb = 0; kb < NKB1; ++kb) {
        h16x8 bf  = *(const h16x8*)(bbase + kb * 32);
        h16x8 af0 = pk8(*(const f32x4*)(a0 + kb * 32), *(const f32x4*)(a0 + kb * 32 + 4));
        h16x8 af1 = pk8(*(const f32x4*)(a1 + kb * 32), *(const f32x4*)(a1 + kb * 32 + 4));
        acc0 = __builtin_amdgcn_mfma_f32_16x16x32_f16(af0, bf, acc0, 0, 0, 0);
        acc1 = __builtin_amdgcn_mfma_f32_16x16x32_f16(af1, bf, acc1, 0, 0, 0);
      }
    } else {
      const u16* hb = h0ring + (size_t)(t & 7) * (B_ * H_);
      const u16* a0 = hb + (size_t)mRow0 * H_ + koffA;
      const u16* a1 = hb + (size_t)mRow1 * H_ + koffA;
#pragma unroll
      for (int kb = 0; kb < NKB1; ++kb) {
        h16x8 bf  = *(const h16x8*)(bbase + kb * 32);
        h16x8 af0 = *(const h16x8*)(a0 + kb * 32);
        h16x8 af1 = *(const h16x8*)(a1 + kb * 32);
        acc0 = __builtin_amdgcn_mfma_f32_16x16x32_f16(af0, bf, acc0, 0, 0, 0);
        acc1 = __builtin_amdgcn_mfma_f32_16x16x32_f16(af1, bf, acc1, 0, 0, 0);
      }
    }
    // part 2: W_hh * h_{t-1}  (skip at t==0: h_{-1}=0)
    if (t > 0) {
      const u16* hb = LAYER ? (h1ring + (size_t)((t - 1) & 3) * (B_ * H_))
                            : (h0ring + (size_t)((t - 1) & 7) * (B_ * H_));
      const u16* r0 = hb + (size_t)mRow0 * H_ + koffA;
      const u16* r1 = hb + (size_t)mRow1 * H_ + koffA;
      const _Float16* bb2 = bbase + KIH;
#pragma unroll
      for (int kb = 0; kb < 16; ++kb) {
        h16x8 bf  = *(const h16x8*)(bb2 + kb * 32);
        h16x8 af0 = *(const h16x8*)(r0 + kb * 32);
        h16x8 af1 = *(const h16x8*)(r1 + kb * 32);
        acc0 = __builtin_amdgcn_mfma_f32_16x16x32_f16(af0, bf, acc0, 0, 0, 0);
        acc1 = __builtin_amdgcn_mfma_f32_16x16x32_f16(af1, bf, acc1, 0, 0, 0);
      }
    }

    // ---- elementwise gate math + h/c update (all fp32) ----
    u16* ringW = LAYER ? (h1ring + (size_t)(t & 3) * (B_ * H_))
                       : (h0ring + (size_t)(t & 7) * (B_ * H_));
    const bool lastT = (t == T_ - 1);
#pragma unroll
    for (int mt = 0; mt < 2; ++mt) {
      f32x4& acc = mt ? acc1 : acc0;
#pragma unroll
      for (int r = 0; r < 4; ++r) {
        float pre = acc[r] + bias;
        float vi = __shfl(pre, 0, 4);   // quad lanes hold i,f,g,o of one unit
        float vf = __shfl(pre, 1, 4);
        float vg = __shfl(pre, 2, 4);
        float vo = __shfl(pre, 3, 4);
        float cnv = sigmf(vf) * cstate[mt][r] + sigmf(vi) * tanhf(vg);
        cstate[mt][r] = cnv;
        float hv = sigmf(vo) * tanhf(cnv);
        if ((lane & 3) == 0) {
          const int m = g * 32 + mt * 16 + quad * 4 + r;   // C/D row mapping
          _Float16 hh = (_Float16)hv;                      // RTN
          ringW[(size_t)m * H_ + jglob] = *(const u16*)&hh;
          if (lastT) {
            out[64 + LAYER * (B_ * H_) + m * H_ + jglob] = hv;                  // hn
            out[64 + 2 * (B_ * H_) + LAYER * (B_ * H_) + m * H_ + jglob] = cnv; // cn
          }
        }
      }
    }

    __syncthreads();
    if (tid == 0) {
      __threadfence();  // release: h slice visible before flag
      atomicAdd(&myDone[g * T_ + t], 1u);
    }
  }
}

__global__ void __launch_bounds__(256, 1) lstm_kernel(
    const float* x,
    const float* Wih0, const float* Whh0, const float* bih0, const float* bhh0,
    const float* Wih1, const float* Whh1, const float* bih1, const float* bhh1,
    float* out, unsigned* done0, unsigned* done1, u16* h0ring, u16* h1ring)
{
  extern __shared__ char smem[];
  _Float16* wlds = (_Float16*)smem;
  const int bid = blockIdx.x;
  const int g = (bid >> 1) & 1;
  const int j0 = (bid >> 2) * 16;
  if ((bid & 1) == 0)
    lstm_body<0>(x, Wih0, Whh0, bih0, bhh0, out, done0, done1, h0ring, h1ring, wlds, g, j0);
  else
    lstm_body<1>(x, Wih1, Whh1, bih1, bhh1, out, done0, done1, h0ring, h1ring, wlds, g, j0);
}

__global__ void init_kernel(unsigned* p, int nw) {
  int i = blockIdx.x * blockDim.x + threadIdx.x;
  if (i < nw) p[i] = 0;
}

__global__ void fc_kernel(const u16* __restrict__ h1last,
                          const float* __restrict__ fcw,
                          const float* __restrict__ fcb,
                          float* __restrict__ out) {
  const int tid = threadIdx.x;
  const int b = tid >> 2, q = tid & 3;
  const u16* hr = h1last + b * H_ + q * 128;
  const float* wr = fcw + q * 128;
  float s = 0.f;
  for (int i = 0; i < 128; ++i) {
    _Float16 hh = *(const _Float16*)&hr[i];
    s += (float)hh * wr[i];
  }
  s += __shfl_xor(s, 1, 4);
  s += __shfl_xor(s, 2, 4);
  if (q == 0) out[b] = s + fcb[0];
}

extern "C" void kernel_launch(void* const* d_in, const int* in_sizes, int n_in,
                              void* d_out, int out_size, void* d_ws, size_t ws_size,
                              hipStream_t stream) {
  const float* x    = (const float*)d_in[0];
  const float* Wih0 = (const float*)d_in[1];
  const float* Whh0 = (const float*)d_in[2];
  const float* bih0 = (const float*)d_in[3];
  const float* bhh0 = (const float*)d_in[4];
  const float* Wih1 = (const float*)d_in[5];
  const float* Whh1 = (const float*)d_in[6];
  const float* bih1 = (const float*)d_in[7];
  const float* bhh1 = (const float*)d_in[8];
  const float* fcw  = (const float*)d_in[9];
  const float* fcb  = (const float*)d_in[10];
  float* out = (float*)d_out;

  // workspace layout (ws re-poisoned each call -> init kernel zeroes flags)
  unsigned* done0 = (unsigned*)d_ws;             // [2][512] u32
  unsigned* done1 = done0 + 2 * T_;              // [2][512] u32
  u16* h0ring = (u16*)((char*)d_ws + 8192);      // [8][64][512] fp16 (512 KB)
  u16* h1ring = h0ring + 8 * B_ * H_;            // [4][64][512] fp16 (256 KB)

  init_kernel<<<8, 256, 0, stream>>>(done0, 2 * 2 * T_);

  const int ldsBytes = 64 * (1024 + 8) * 2;      // 132096 B (proven to launch in R1)
  (void)hipFuncSetAttribute((const void*)lstm_kernel,
                            hipFuncAttributeMaxDynamicSharedMemorySize, ldsBytes);
  // 128 WGs: (layer, batch-group, j-slice). All co-resident (1 WG/CU by LDS).
  lstm_kernel<<<128, 256, ldsBytes, stream>>>(x, Wih0, Whh0, bih0, bhh0,
                                              Wih1, Whh1, bih1, bhh1,
                                              out, done0, done1, h0ring, h1ring);
  fc_kernel<<<1, 256, 0, stream>>>(h1ring + (size_t)((T_ - 1) & 3) * (B_ * H_),
                                   fcw, fcb, out);
}

// Round 4
// 8542.289 us; speedup vs baseline: 1.4158x; 1.4158x over previous
//
#include <hip/hip_runtime.h>
#include <hip/hip_bf16.h>

#define B_   64
#define T_   512
#define DIN_ 256
#define H_   512

typedef __attribute__((ext_vector_type(2))) _Float16 h16x2;
typedef __attribute__((ext_vector_type(8))) _Float16 h16x8;
typedef __attribute__((ext_vector_type(2))) __fp16  fp16x2r;  // cvt_pkrtz return type
typedef __attribute__((ext_vector_type(4))) float f32x4;
typedef unsigned short u16;
typedef unsigned long long u64;

__device__ __forceinline__ float sigmf(float xv) {
  return 1.0f / (1.0f + __expf(-xv));
}

// All-lane relaxed agent-scope poll. Device-scope atomics are MALL-coherent
// across XCDs with NO cache maintenance (the R3 23.6us/step was threadfence's
// buffer_wbl2/inv per step). Guard valve: never hang the harness.
__device__ __forceinline__ void waitflag(unsigned* p, unsigned target) {
  int guard = 0;
  while (__hip_atomic_load(p, __ATOMIC_RELAXED, __HIP_MEMORY_SCOPE_AGENT) < target) {
    if (++guard > (1 << 20)) break;
  }
}

// 16B ring chunk as two 8B relaxed agent atomic loads (coherent at MALL).
__device__ __forceinline__ h16x8 ldring(const u16* p) {
  union { h16x8 h; u64 q[2]; } u;
  u.q[0] = __hip_atomic_load((u64*)p,       __ATOMIC_RELAXED, __HIP_MEMORY_SCOPE_AGENT);
  u.q[1] = __hip_atomic_load((u64*)(p + 4), __ATOMIC_RELAXED, __HIP_MEMORY_SCOPE_AGENT);
  return u.h;
}

__device__ __forceinline__ h16x8 pk8(f32x4 a, f32x4 b) {
  union { h16x8 h; fp16x2r p[4]; } u;   // __fp16 member matches cvt_pkrtz return
  u.p[0] = __builtin_amdgcn_cvt_pkrtz(a.x, a.y);
  u.p[1] = __builtin_amdgcn_cvt_pkrtz(a.z, a.w);
  u.p[2] = __builtin_amdgcn_cvt_pkrtz(b.x, b.y);
  u.p[3] = __builtin_amdgcn_cvt_pkrtz(b.z, b.w);
  return u.h;
}

// Persistent per-WG LSTM slice; fp32 global data, fp16 MFMA compute, fp32 c.
// Sync protocol (R4): flag = relaxed agent atomicAdd per WAVE (target 128 =
// 32 WG x 4 waves per (layer,group) domain); h rings written as u32 packed
// fp16 relaxed agent atomic stores, read as u64 relaxed agent atomic loads.
// Release ordering: s_waitcnt(0) after stores (acks at MALL) before flag add.
// No __threadfence, no per-step __syncthreads: waves free-run, skew <= 1 step
// (flag chain), ring depths 8/4 cover reuse distance.
template <int LAYER>
__device__ __forceinline__ void lstm_body(
    const float* __restrict__ xin,
    const float* __restrict__ Wih, const float* __restrict__ Whh,
    const float* __restrict__ bih, const float* __restrict__ bhh,
    float* __restrict__ out,
    unsigned* __restrict__ done0, unsigned* __restrict__ done1,
    u16* __restrict__ h0ring, u16* __restrict__ h1ring,
    _Float16* wlds, int g, int j0)
{
  constexpr int K    = LAYER ? 1024 : 768;   // Kih + 512 (recurrent)
  constexpr int KP   = K + 8;                // pad keeps rows 16B-aligned, breaks bank stride
  constexpr int KIH  = LAYER ? 512 : 256;
  constexpr int NKB1 = KIH / 32;
  const int tid = threadIdx.x;

  // ---- one-time: stage W slice (64 rows x K) f32 -> fp16 LDS ----
  {
    const int c = tid;                       // float4 chunk within a row
    if (c < (K >> 2)) {
      for (int rho = 0; rho < 64; ++rho) {
        const int gI = rho & 3, jI = (rho >> 2) & 3, nt = rho >> 4;
        const int gr = gI * H_ + j0 + nt * 4 + jI;   // global gate-row
        f32x4 v;
        if (c < (KIH >> 2))
          v = *(const f32x4*)(Wih + (size_t)gr * KIH + (size_t)c * 4);
        else
          v = *(const f32x4*)(Whh + (size_t)gr * H_ + (size_t)(c - (KIH >> 2)) * 4);
        h16x2 q0, q1;                        // scalar casts: RTN rounding for weights
        q0[0] = (_Float16)v.x; q0[1] = (_Float16)v.y;
        q1[0] = (_Float16)v.z; q1[1] = (_Float16)v.w;
        *(h16x2*)(wlds + rho * KP + c * 4)     = q0;
        *(h16x2*)(wlds + rho * KP + c * 4 + 2) = q1;
      }
    }
  }

  const int lane = tid & 63;
  const int w    = tid >> 6;        // wave id == N-tile id
  const int n    = lane & 15;       // output col within 16-wide tile
  const int quad = lane >> 4;
  const int gI   = n & 3;           // gate of this lane's column
  const int jI   = n >> 2;
  const int jglob = j0 + w * 4 + jI;
  const float bias = bih[gI * H_ + jglob] + bhh[gI * H_ + jglob];

  const int mRow0 = g * 32 + n;          // A-operand rows (m = lane&15)
  const int mRow1 = g * 32 + 16 + n;
  const int koffA = quad * 8;            // k offset within 32-wide k-block
  const _Float16* bbase = wlds + (w * 16 + n) * KP + koffA;

  __syncthreads();   // staging done (only barrier in the kernel)

  f32x4 cstate[2] = {{0.f,0.f,0.f,0.f},{0.f,0.f,0.f,0.f}};
  unsigned* myDone = LAYER ? done1 : done0;

  for (int t = 0; t < T_; ++t) {
    f32x4 acc0 = {0.f,0.f,0.f,0.f}, acc1 = {0.f,0.f,0.f,0.f};

    // ---- part 1: W_ih * input_t ----
    // L0: x is immutable global (normal cached loads) and has NO recurrent
    // dependency -> computed BEFORE any flag wait (overlaps peer skew).
    if (LAYER == 0) {
      const float* a0 = xin + (size_t)mRow0 * (T_ * DIN_) + (size_t)t * DIN_ + koffA;
      const float* a1 = xin + (size_t)mRow1 * (T_ * DIN_) + (size_t)t * DIN_ + koffA;
#pragma unroll
      for (int kb = 0; kb < NKB1; ++kb) {
        h16x8 bf  = *(const h16x8*)(bbase + kb * 32);
        h16x8 af0 = pk8(*(const f32x4*)(a0 + kb * 32), *(const f32x4*)(a0 + kb * 32 + 4));
        h16x8 af1 = pk8(*(const f32x4*)(a1 + kb * 32), *(const f32x4*)(a1 + kb * 32 + 4));
        acc0 = __builtin_amdgcn_mfma_f32_16x16x32_f16(af0, bf, acc0, 0, 0, 0);
        acc1 = __builtin_amdgcn_mfma_f32_16x16x32_f16(af1, bf, acc1, 0, 0, 0);
      }
    } else {
      // L1 input = h0[t]: wait producer domain, then coherent ring loads.
      waitflag(&done0[g * T_ + t], 128);
      const u16* hb = h0ring + (size_t)(t & 7) * (B_ * H_);
      const u16* a0 = hb + (size_t)mRow0 * H_ + koffA;
      const u16* a1 = hb + (size_t)mRow1 * H_ + koffA;
#pragma unroll
      for (int kb = 0; kb < NKB1; ++kb) {
        h16x8 bf  = *(const h16x8*)(bbase + kb * 32);
        h16x8 af0 = ldring(a0 + kb * 32);
        h16x8 af1 = ldring(a1 + kb * 32);
        acc0 = __builtin_amdgcn_mfma_f32_16x16x32_f16(af0, bf, acc0, 0, 0, 0);
        acc1 = __builtin_amdgcn_mfma_f32_16x16x32_f16(af1, bf, acc1, 0, 0, 0);
      }
    }

    // ---- part 2: W_hh * h_{t-1} (skip at t==0) ----
    if (t > 0) {
      if (LAYER == 0) waitflag(&done0[g * T_ + t - 1], 128);
      else            waitflag(&done1[g * T_ + t - 1], 128);
      const u16* hb = LAYER ? (h1ring + (size_t)((t - 1) & 3) * (B_ * H_))
                            : (h0ring + (size_t)((t - 1) & 7) * (B_ * H_));
      const u16* r0 = hb + (size_t)mRow0 * H_ + koffA;
      const u16* r1 = hb + (size_t)mRow1 * H_ + koffA;
      const _Float16* bb2 = bbase + KIH;
#pragma unroll
      for (int kb = 0; kb < 16; ++kb) {
        h16x8 bf  = *(const h16x8*)(bb2 + kb * 32);
        h16x8 af0 = ldring(r0 + kb * 32);
        h16x8 af1 = ldring(r1 + kb * 32);
        acc0 = __builtin_amdgcn_mfma_f32_16x16x32_f16(af0, bf, acc0, 0, 0, 0);
        acc1 = __builtin_amdgcn_mfma_f32_16x16x32_f16(af1, bf, acc1, 0, 0, 0);
      }
    }

    // ring backpressure before overwriting slot t&7 (L0 only; h1 depth 4
    // is covered by the <=1-step wave skew from the flag chain)
    if (LAYER == 0 && t >= 8) waitflag(&done1[g * T_ + t - 8], 128);

    // ---- elementwise gate math + h/c update (fp32) ----
    u16* ringW = LAYER ? (h1ring + (size_t)(t & 3) * (B_ * H_))
                       : (h0ring + (size_t)(t & 7) * (B_ * H_));
    const bool lastT = (t == T_ - 1);
#pragma unroll
    for (int mt = 0; mt < 2; ++mt) {
      f32x4& acc = mt ? acc1 : acc0;
#pragma unroll
      for (int r = 0; r < 4; ++r) {
        float pre = acc[r] + bias;
        float vi = __shfl(pre, 0, 4);   // quad lanes hold i,f,g,o of one unit
        float vf = __shfl(pre, 1, 4);
        float vg = __shfl(pre, 2, 4);
        float vo = __shfl(pre, 3, 4);
        float cnv = sigmf(vf) * cstate[mt][r] + sigmf(vi) * tanhf(vg);
        cstate[mt][r] = cnv;
        float hv = sigmf(vo) * tanhf(cnv);
        float hv2 = __shfl(hv, lane + 4);   // partner column (n+4); used by n in {0,8}
        if ((lane & 7) == 0) {              // n==0 / n==8: pack 2 adjacent cols -> u32
          const int m = g * 32 + mt * 16 + quad * 4 + r;   // C/D row mapping
          _Float16 ha = (_Float16)hv;       // RTN (keep R3 numerics)
          _Float16 hb2 = (_Float16)hv2;
          union { struct { u16 a, b; } s; unsigned u; } pku;
          pku.s.a = *(const u16*)&ha; pku.s.b = *(const u16*)&hb2;
          __hip_atomic_store((unsigned*)&ringW[(size_t)m * H_ + jglob], pku.u,
                             __ATOMIC_RELAXED, __HIP_MEMORY_SCOPE_AGENT);
        }
        if (lastT && (lane & 3) == 0) {
          const int m = g * 32 + mt * 16 + quad * 4 + r;
          out[64 + LAYER * (B_ * H_) + m * H_ + jglob] = hv;                  // hn
          out[64 + 2 * (B_ * H_) + LAYER * (B_ * H_) + m * H_ + jglob] = cnv; // cn
        }
      }
    }

    // ---- per-wave release: drain store acks (data at MALL), then flag ----
    __builtin_amdgcn_s_waitcnt(0);
    if (lane == 0)
      __hip_atomic_fetch_add(&myDone[g * T_ + t], 1u,
                             __ATOMIC_RELAXED, __HIP_MEMORY_SCOPE_AGENT);
  }
}

__global__ void __launch_bounds__(256, 1) lstm_kernel(
    const float* x,
    const float* Wih0, const float* Whh0, const float* bih0, const float* bhh0,
    const float* Wih1, const float* Whh1, const float* bih1, const float* bhh1,
    float* out, unsigned* done0, unsigned* done1, u16* h0ring, u16* h1ring)
{
  extern __shared__ char smem[];
  _Float16* wlds = (_Float16*)smem;
  const int bid = blockIdx.x;
  const int g = (bid >> 1) & 1;
  const int j0 = (bid >> 2) * 16;
  if ((bid & 1) == 0)
    lstm_body<0>(x, Wih0, Whh0, bih0, bhh0, out, done0, done1, h0ring, h1ring, wlds, g, j0);
  else
    lstm_body<1>(x, Wih1, Whh1, bih1, bhh1, out, done0, done1, h0ring, h1ring, wlds, g, j0);
}

__global__ void init_kernel(unsigned* p, int nw) {
  int i = blockIdx.x * blockDim.x + threadIdx.x;
  if (i < nw) p[i] = 0;
}

__global__ void fc_kernel(const u16* __restrict__ h1last,
                          const float* __restrict__ fcw,
                          const float* __restrict__ fcb,
                          float* __restrict__ out) {
  const int tid = threadIdx.x;
  const int b = tid >> 2, q = tid & 3;
  const u16* hr = h1last + b * H_ + q * 128;
  const float* wr = fcw + q * 128;
  float s = 0.f;
  for (int i = 0; i < 128; ++i) {
    _Float16 hh = *(const _Float16*)&hr[i];
    s += (float)hh * wr[i];
  }
  s += __shfl_xor(s, 1, 4);
  s += __shfl_xor(s, 2, 4);
  if (q == 0) out[b] = s + fcb[0];
}

extern "C" void kernel_launch(void* const* d_in, const int* in_sizes, int n_in,
                              void* d_out, int out_size, void* d_ws, size_t ws_size,
                              hipStream_t stream) {
  const float* x    = (const float*)d_in[0];
  const float* Wih0 = (const float*)d_in[1];
  const float* Whh0 = (const float*)d_in[2];
  const float* bih0 = (const float*)d_in[3];
  const float* bhh0 = (const float*)d_in[4];
  const float* Wih1 = (const float*)d_in[5];
  const float* Whh1 = (const float*)d_in[6];
  const float* bih1 = (const float*)d_in[7];
  const float* bhh1 = (const float*)d_in[8];
  const float* fcw  = (const float*)d_in[9];
  const float* fcb  = (const float*)d_in[10];
  float* out = (float*)d_out;

  // workspace layout (ws re-poisoned each call -> init kernel zeroes flags)
  unsigned* done0 = (unsigned*)d_ws;             // [2][512] u32
  unsigned* done1 = done0 + 2 * T_;              // [2][512] u32
  u16* h0ring = (u16*)((char*)d_ws + 8192);      // [8][64][512] fp16 (512 KB)
  u16* h1ring = h0ring + 8 * B_ * H_;            // [4][64][512] fp16 (256 KB)

  init_kernel<<<8, 256, 0, stream>>>(done0, 2 * 2 * T_);

  const int ldsBytes = 64 * (1024 + 8) * 2;      // 132096 B
  (void)hipFuncSetAttribute((const void*)lstm_kernel,
                            hipFuncAttributeMaxDynamicSharedMemorySize, ldsBytes);
  // 128 WGs: (layer, batch-group, j-slice). All co-resident (1 WG/CU by LDS).
  lstm_kernel<<<128, 256, ldsBytes, stream>>>(x, Wih0, Whh0, bih0, bhh0,
                                              Wih1, Whh1, bih1, bhh1,
                                              out, done0, done1, h0ring, h1ring);
  fc_kernel<<<1, 256, 0, stream>>>(h1ring + (size_t)((T_ - 1) & 3) * (B_ * H_),
                                   fcw, fcb, out);
}